// Round 6
// baseline (563.833 us; speedup 1.0000x reference)
//
#include <hip/hip_runtime.h>
#include <cstdint>
#include <cstddef>

#define DEV __device__ __forceinline__

typedef _Float16 f16x8 __attribute__((ext_vector_type(8)));
typedef float f32x4 __attribute__((ext_vector_type(4)));

static constexpr int D_MODEL = 2048;
static constexpr int D_FF    = 5632;
static constexpr int N_QKV   = 3072;   // 2048 q + 512 k + 512 v
static constexpr int SEQ     = 1024;
static constexpr int BATCH   = 2;
static constexpr int ROWS    = BATCH * SEQ;  // 2048
static constexpr int HEADS   = 16;
static constexpr int HD      = 128;

DEV uint16_t f2h(float f) {
    return __builtin_bit_cast(uint16_t, (_Float16)f);   // RTNE, 2^-12 RMS rel err
}

// async global->LDS, 16B/lane; lds ptr must be wave-uniform (HW adds lane*16)
DEV void async_load16(const void* g, void* lds) {
    __builtin_amdgcn_global_load_lds(
        reinterpret_cast<__attribute__((address_space(1))) void*>(
            reinterpret_cast<uintptr_t>(g)),
        reinterpret_cast<__attribute__((address_space(3))) void*>(
            static_cast<uint32_t>(reinterpret_cast<uintptr_t>(lds))),
        16, 0, 0);
}

// ---------------------------------------------------------------------------
// Merged dequant: ALL 7 weight tensors in one launch (static segment table).
// w = q*s (fp32) -> fp16. mode 0: orow=row; 1: gate interleave; 2: up.
// ---------------------------------------------------------------------------
static constexpr int DQ_BLOCKS = 44032;

__global__ __launch_bounds__(256)
void dequant_all_kernel(const int* __restrict__ wq_q, const float* __restrict__ wq_s,
                        const int* __restrict__ wk_q, const float* __restrict__ wk_s,
                        const int* __restrict__ wv_q, const float* __restrict__ wv_s,
                        const int* __restrict__ wo_q, const float* __restrict__ wo_s,
                        const int* __restrict__ gate_q, const float* __restrict__ gate_s,
                        const int* __restrict__ up_q, const float* __restrict__ up_s,
                        const int* __restrict__ down_q, const float* __restrict__ down_s,
                        uint16_t* __restrict__ Wqkv, uint16_t* __restrict__ Wo,
                        uint16_t* __restrict__ Wgu, uint16_t* __restrict__ Wdown)
{
    const int bid = blockIdx.x;
    const int* q; const float* s; uint16_t* out; int I, mode, seg0;
    if (bid < 4096)        { q = wq_q;   s = wq_s;   out = Wqkv;                      I = 2048; mode = 0; seg0 = 0; }
    else if (bid < 5120)   { q = wk_q;   s = wk_s;   out = Wqkv + 2048 * 2048;        I = 2048; mode = 0; seg0 = 4096; }
    else if (bid < 6144)   { q = wv_q;   s = wv_s;   out = Wqkv + 2560 * 2048;        I = 2048; mode = 0; seg0 = 5120; }
    else if (bid < 10240)  { q = wo_q;   s = wo_s;   out = Wo;                        I = 2048; mode = 0; seg0 = 6144; }
    else if (bid < 21504)  { q = gate_q; s = gate_s; out = Wgu;                       I = 2048; mode = 1; seg0 = 10240; }
    else if (bid < 32768)  { q = up_q;   s = up_s;   out = Wgu;                       I = 2048; mode = 2; seg0 = 21504; }
    else                   { q = down_q; s = down_s; out = Wdown;                     I = 5632; mode = 0; seg0 = 32768; }

    const int idx = (bid - seg0) * 256 + threadIdx.x;
    const int e = idx * 4;
    const int row = e / I;
    const int i = e - row * I;
    const int4 qv = *reinterpret_cast<const int4*>(&q[e]);
    const float scf = s[row * (I >> 6) + (i >> 6)];
    int orow = row;
    if (mode == 1) orow = ((row >> 4) << 5) + (row & 15);
    else if (mode == 2) orow = ((row >> 4) << 5) + (row & 15) + 16;
    uint16_t h[4];
    h[0] = f2h((float)qv.x * scf);
    h[1] = f2h((float)qv.y * scf);
    h[2] = f2h((float)qv.z * scf);
    h[3] = f2h((float)qv.w * scf);
    uint2 pk;
    pk.x = (uint32_t)h[0] | ((uint32_t)h[1] << 16);
    pk.y = (uint32_t)h[2] | ((uint32_t)h[3] << 16);
    *reinterpret_cast<uint2*>(&out[(size_t)orow * I + i]) = pk;
}

// ---------------------------------------------------------------------------
// RMSNorm (fp32 in) -> fp16. One row (2048) per block of 256.
// ---------------------------------------------------------------------------
__global__ __launch_bounds__(256)
void rmsnorm_kernel(const float* __restrict__ x, const float* __restrict__ wln,
                    uint16_t* __restrict__ out)
{
    __shared__ float red[4];
    const int row = blockIdx.x;
    const int tid = threadIdx.x;
    const float* xr = x + (size_t)row * D_MODEL;
    const float4 v0 = *reinterpret_cast<const float4*>(&xr[tid * 8]);
    const float4 v1 = *reinterpret_cast<const float4*>(&xr[tid * 8 + 4]);
    float ss = v0.x*v0.x + v0.y*v0.y + v0.z*v0.z + v0.w*v0.w
             + v1.x*v1.x + v1.y*v1.y + v1.z*v1.z + v1.w*v1.w;
#pragma unroll
    for (int off = 32; off; off >>= 1) ss += __shfl_xor(ss, off);
    if ((tid & 63) == 0) red[tid >> 6] = ss;
    __syncthreads();
    const float rms = rsqrtf((red[0] + red[1] + red[2] + red[3]) * (1.0f / D_MODEL) + 1e-6f);
    const int cb = tid * 8;
    const size_t base = (size_t)row * D_MODEL + cb;
    const float vals[8] = {v0.x, v0.y, v0.z, v0.w, v1.x, v1.y, v1.z, v1.w};
#pragma unroll
    for (int k = 0; k < 8; k += 2) {
        const uint16_t h0 = f2h(vals[k] * rms * wln[cb + k]);
        const uint16_t h1 = f2h(vals[k + 1] * rms * wln[cb + k + 1]);
        *reinterpret_cast<uint32_t*>(&out[base + k]) = (uint32_t)h0 | ((uint32_t)h1 << 16);
    }
}

// ---------------------------------------------------------------------------
// fp16 GEMM, 128x128 tile (fused SwiGLU epilogue, gate/up interleaved W).
// Round-3 verified config (row-major block map, NO xcd remap — round-5 A/B:
// remap cost +4 us and +17 MB FETCH). BK=64, A+B double-buffered LDS, ONE
// barrier per K-tile. Both-sides swizzle: granule p at row r holds logical
// p^(r&7); ds_read applies same XOR -> 2-way banks (free).
// ---------------------------------------------------------------------------
__global__ __launch_bounds__(256)
void gemm_f16_glu_kernel(const uint16_t* __restrict__ A, const uint16_t* __restrict__ W,
                         uint16_t* __restrict__ outh, int M, int N, int K)
{
    __shared__ uint16_t sA[2][128 * 64];
    __shared__ uint16_t sB[2][128 * 64];

    const int tid  = threadIdx.x;
    const int lane = tid & 63;
    const int wv   = tid >> 6;
    const int wm   = wv >> 1;
    const int wn   = wv & 1;
    const int quad = lane >> 4;
    const int l16  = lane & 15;

    const int nBn = N >> 7;
    const int bm  = blockIdx.x / nBn;
    const int bn  = blockIdx.x - bm * nBn;
    const int m0  = bm << 7;
    const int n0  = bn << 7;

    f32x4 acc[4][4];
#pragma unroll
    for (int i = 0; i < 4; i++)
#pragma unroll
        for (int j = 0; j < 4; j++)
            acc[i][j] = (f32x4){0.f, 0.f, 0.f, 0.f};

    const uint16_t* Ab = A + (size_t)m0 * K;
    const uint16_t* Wb = W + (size_t)n0 * K;

    auto stage = [&](int kt, int bsel) {
#pragma unroll
        for (int p = 0; p < 4; p++) {
            const int cb = p * 256 + wv * 64;          // wave-uniform chunk base
            const int c  = cb + lane;
            const int row = c >> 3;
            const int g   = (c & 7) ^ (row & 7);       // pre-swizzled source
            const size_t goff = (size_t)row * K + kt + g * 8;
            async_load16(Ab + goff, &sA[bsel][cb * 8]);
            async_load16(Wb + goff, &sB[bsel][cb * 8]);
        }
    };

    stage(0, 0);
    __syncthreads();

    const int nKt = K >> 6;
    for (int t = 0; t < nKt; t++) {
        const int cur = t & 1;
        if (t + 1 < nKt) stage((t + 1) << 6, cur ^ 1);
        const uint16_t* sAc = sA[cur];
        const uint16_t* sBc = sB[cur];
#pragma unroll
        for (int kk = 0; kk < 2; kk++) {
            const int gsw = ((kk * 4 + quad) ^ (l16 & 7)) * 8;   // swizzled read granule
            f16x8 bfv[4];
#pragma unroll
            for (int j = 0; j < 4; j++)
                bfv[j] = *reinterpret_cast<const f16x8*>(
                    &sBc[(wn * 64 + j * 16 + l16) * 64 + gsw]);
#pragma unroll
            for (int i = 0; i < 4; i++) {
                const f16x8 af = *reinterpret_cast<const f16x8*>(
                    &sAc[(wm * 64 + i * 16 + l16) * 64 + gsw]);
#pragma unroll
                for (int j = 0; j < 4; j++)
                    acc[i][j] = __builtin_amdgcn_mfma_f32_16x16x32_f16(af, bfv[j], acc[i][j], 0, 0, 0);
            }
        }
        __syncthreads();   // drains vmcnt (t+1 loads) + syncs reads of buf[cur]
    }

    // SwiGLU: j even = gate, j odd = up of same 16-col group.
    const int NH = N >> 1;
#pragma unroll
    for (int i = 0; i < 4; i++) {
        const int rowb = m0 + wm * 64 + i * 16 + quad * 4;
#pragma unroll
        for (int r = 0; r < 4; r++) {
            const size_t rr = (size_t)(rowb + r);
#pragma unroll
            for (int pjt = 0; pjt < 2; pjt++) {
                const float g = acc[i][2 * pjt][r];
                const float u = acc[i][2 * pjt + 1][r];
                const float a = (g / (1.0f + __expf(-g))) * u;
                const int cc = (n0 >> 1) + wn * 32 + pjt * 16 + l16;
                outh[rr * NH + cc] = f2h(a);
            }
        }
    }
}

// ---------------------------------------------------------------------------
// fp16 GEMM, 128x128 tile, fp32 out (+QKV-bias select / +resid). EXACT same
// K-loop as the GLU kernel (proven round-3 schedule); only the epilogue
// differs. Replaces the 64x128 kernel: per K-tile per wave this shape does
// 32 MFMA on 16 ds_read_b128 (0.5 reads/MFMA) vs m64's 16 on 12 (0.75).
// ---------------------------------------------------------------------------
__global__ __launch_bounds__(256)
void gemm_f16_m128_kernel(const uint16_t* __restrict__ A, const uint16_t* __restrict__ W,
                          const float* __restrict__ bq, const float* __restrict__ bk,
                          const float* __restrict__ bv, const float* __restrict__ resid,
                          float* __restrict__ outf, int M, int N, int K)
{
    __shared__ uint16_t sA[2][128 * 64];
    __shared__ uint16_t sB[2][128 * 64];

    const int tid  = threadIdx.x;
    const int lane = tid & 63;
    const int wv   = tid >> 6;
    const int wm   = wv >> 1;
    const int wn   = wv & 1;
    const int quad = lane >> 4;
    const int l16  = lane & 15;

    const int nBn = N >> 7;
    const int bm  = blockIdx.x / nBn;
    const int bn  = blockIdx.x - bm * nBn;
    const int m0  = bm << 7;
    const int n0  = bn << 7;

    f32x4 acc[4][4];
#pragma unroll
    for (int i = 0; i < 4; i++)
#pragma unroll
        for (int j = 0; j < 4; j++)
            acc[i][j] = (f32x4){0.f, 0.f, 0.f, 0.f};

    const uint16_t* Ab = A + (size_t)m0 * K;
    const uint16_t* Wb = W + (size_t)n0 * K;

    auto stage = [&](int kt, int bsel) {
#pragma unroll
        for (int p = 0; p < 4; p++) {
            const int cb = p * 256 + wv * 64;
            const int c  = cb + lane;
            const int row = c >> 3;
            const int g   = (c & 7) ^ (row & 7);
            const size_t goff = (size_t)row * K + kt + g * 8;
            async_load16(Ab + goff, &sA[bsel][cb * 8]);
            async_load16(Wb + goff, &sB[bsel][cb * 8]);
        }
    };

    stage(0, 0);
    __syncthreads();

    const int nKt = K >> 6;
    for (int t = 0; t < nKt; t++) {
        const int cur = t & 1;
        if (t + 1 < nKt) stage((t + 1) << 6, cur ^ 1);
        const uint16_t* sAc = sA[cur];
        const uint16_t* sBc = sB[cur];
#pragma unroll
        for (int kk = 0; kk < 2; kk++) {
            const int gsw = ((kk * 4 + quad) ^ (l16 & 7)) * 8;
            f16x8 bfv[4];
#pragma unroll
            for (int j = 0; j < 4; j++)
                bfv[j] = *reinterpret_cast<const f16x8*>(
                    &sBc[(wn * 64 + j * 16 + l16) * 64 + gsw]);
#pragma unroll
            for (int i = 0; i < 4; i++) {
                const f16x8 af = *reinterpret_cast<const f16x8*>(
                    &sAc[(wm * 64 + i * 16 + l16) * 64 + gsw]);
#pragma unroll
                for (int j = 0; j < 4; j++)
                    acc[i][j] = __builtin_amdgcn_mfma_f32_16x16x32_f16(af, bfv[j], acc[i][j], 0, 0, 0);
            }
        }
        __syncthreads();
    }

    // epilogue: C row = quad*4+reg, col = lane&15 (m89-verified)
#pragma unroll
    for (int i = 0; i < 4; i++) {
        const int rowb = m0 + wm * 64 + i * 16 + quad * 4;
#pragma unroll
        for (int r = 0; r < 4; r++) {
            const size_t rr = (size_t)(rowb + r);
#pragma unroll
            for (int j = 0; j < 4; j++) {
                const int cc = n0 + wn * 64 + j * 16 + l16;
                float v = acc[i][j][r];
                if (bq) {   // QKV bias concat (boundaries are layout consts)
                    float bb;
                    if (cc < 2048)      bb = bq[cc];
                    else if (cc < 2560) bb = bk[cc - 2048];
                    else                bb = bv[cc - 2560];
                    v += bb;
                }
                if (resid) v += resid[rr * N + cc];
                outf[rr * N + cc] = v;
            }
        }
    }
}

// ---------------------------------------------------------------------------
// Merged RoPE prep: Q then K in one launch.
// ---------------------------------------------------------------------------
static constexpr int ROPE_Q_THREADS = ROWS * 16 * 64;   // 2,097,152
static constexpr int ROPE_THREADS   = ROPE_Q_THREADS + ROWS * 4 * 64;

__global__ __launch_bounds__(256)
void rope_qk_kernel(const float* __restrict__ qkv, const int* __restrict__ offp,
                    uint16_t* __restrict__ Qb, uint16_t* __restrict__ Kb)
{
    const int gidx = blockIdx.x * 256 + threadIdx.x;
    if (gidx < ROPE_Q_THREADS) {
        const int idx = gidx;
        const int d   = idx & 63;
        const int h   = (idx >> 6) & 15;
        const int row = idx >> 10;
        const int b   = row >> 10;
        const int s   = row & (SEQ - 1);
        const float pos  = (float)(s + *offp);
        const float freq = powf(1.0e6f, -(float)d * (1.0f / 64.0f));
        float sn, cs;
        sincosf(pos * freq, &sn, &cs);
        const size_t gb = (size_t)row * N_QKV + h * HD + d;
        const float x1 = qkv[gb];
        const float x2 = qkv[gb + 64];
        const float qscale = 0.08838834764831845f;   // 1/sqrt(128)
        const size_t ob = ((size_t)(b * 16 + h) * SEQ + s) * HD + d;
        Qb[ob]      = f2h((x1 * cs - x2 * sn) * qscale);
        Qb[ob + 64] = f2h((x2 * cs + x1 * sn) * qscale);
    } else {
        const int idx = gidx - ROPE_Q_THREADS;
        const int d   = idx & 63;
        const int kvh = (idx >> 6) & 3;
        const int row = idx >> 8;
        const int b   = row >> 10;
        const int s   = row & (SEQ - 1);
        const float pos  = (float)(s + *offp);
        const float freq = powf(1.0e6f, -(float)d * (1.0f / 64.0f));
        float sn, cs;
        sincosf(pos * freq, &sn, &cs);
        const size_t gb = (size_t)row * N_QKV + 2048 + kvh * HD + d;
        const float x1 = qkv[gb];
        const float x2 = qkv[gb + 64];
        const size_t ob = ((size_t)(b * 4 + kvh) * SEQ + s) * HD + d;
        Kb[ob]      = f2h(x1 * cs - x2 * sn);
        Kb[ob + 64] = f2h(x2 * cs + x1 * sn);
    }
}

// V transpose prep: qkv fp32 -> fp16 V^T [(b*4+kvh)*128+dim][1024 keys].
__global__ __launch_bounds__(256)
void prep_v_kernel(const float* __restrict__ qkv, uint16_t* __restrict__ Vt)
{
    __shared__ uint16_t sh[128 * 72];
    const int tid = threadIdx.x;
    const int sc  = blockIdx.x & 15;     // 16 chunks of 64 keys
    const int bk  = blockIdx.x >> 4;     // b*4+kvh
    const int b   = bk >> 2, kvh = bk & 3;
#pragma unroll
    for (int p = 0; p < 8; p++) {
        const int q4 = p * 256 + tid;    // 2048 float4s: 64 rows x 32
        const int sloc = q4 >> 5, d4 = (q4 & 31) * 4;
        const float4 v = *reinterpret_cast<const float4*>(
            &qkv[(size_t)(b * SEQ + sc * 64 + sloc) * N_QKV + 2560 + kvh * HD + d4]);
        sh[(d4 + 0) * 72 + sloc] = f2h(v.x);
        sh[(d4 + 1) * 72 + sloc] = f2h(v.y);
        sh[(d4 + 2) * 72 + sloc] = f2h(v.z);
        sh[(d4 + 3) * 72 + sloc] = f2h(v.w);
    }
    __syncthreads();
    const int d = tid >> 1, half = tid & 1;
    const size_t ob = ((size_t)(bk * 128 + d)) * SEQ + sc * 64 + half * 32;
    const uint16_t* srh = &sh[d * 72 + half * 32];
#pragma unroll
    for (int k = 0; k < 4; k++)
        *reinterpret_cast<uint4*>(&Vt[ob + k * 8]) =
            *reinterpret_cast<const uint4*>(&srh[k * 8]);
}

// ---------------------------------------------------------------------------
// MFMA fp16 flash attention (round-3 verified). Block = 64 Q rows of one
// (b,h); 4 waves x 16 rows. 32-key tiles, double-buffered K/V staging, ONE
// barrier per tile. sP is wave-private. K granule^row swizzle; V^T
// granule^(row>>1) swizzle.
// ---------------------------------------------------------------------------
__global__ __launch_bounds__(256)
void attn_kernel(const uint16_t* __restrict__ Qb, const uint16_t* __restrict__ Kb,
                 const uint16_t* __restrict__ Vt, uint16_t* __restrict__ att)
{
    __shared__ uint16_t sK[2][32 * 128];
    __shared__ uint16_t sV[2][128 * 32];
    __shared__ uint16_t sP[4 * 16 * 32];

    const int tid  = threadIdx.x;
    const int lane = tid & 63;
    const int wv   = tid >> 6;
    const int quad = lane >> 4;
    const int l16  = lane & 15;
    const int qsw  = (quad ^ ((l16 >> 1) & 3)) * 8;   // swizzled V read granule

    const int bi  = blockIdx.x;
    const int sc  = 15 - (bi >> 5);      // big Q-tiles dispatched first
    const int bh  = bi & 31;
    const int b   = bh >> 4;
    const int h   = bh & 15;
    const int kvh = h >> 2;
    const int s0  = sc << 6;

    // Q fragments (A-layout) straight from global, once.
    f16x8 qf[4];
    {
        const size_t qb = ((size_t)(b * 16 + h) * SEQ + s0 + wv * 16 + l16) * HD;
#pragma unroll
        for (int ks = 0; ks < 4; ks++)
            qf[ks] = *reinterpret_cast<const f16x8*>(&Qb[qb + ks * 32 + quad * 8]);
    }

    float m_i[4], l_i[4];
#pragma unroll
    for (int r = 0; r < 4; r++) { m_i[r] = -1e30f; l_i[r] = 0.f; }
    f32x4 oacc[8];
#pragma unroll
    for (int dt = 0; dt < 8; dt++) oacc[dt] = (f32x4){0.f, 0.f, 0.f, 0.f};

    const size_t kb = (size_t)(b * 4 + kvh) * SEQ * HD;        // K base (elems)
    const size_t vb = (size_t)(b * 4 + kvh) * HD * SEQ;        // V^T base

    auto stageKV = [&](int t0, int bsel) {
#pragma unroll
        for (int p = 0; p < 2; p++) {
            const int cb = p * 256 + wv * 64;
            const int c  = cb + lane;
            const int krow = c >> 4;
            const int kcc  = (c & 15) ^ (krow & 7);
            async_load16(Kb + kb + (size_t)(t0 + krow) * HD + kcc * 8, &sK[bsel][cb * 8]);
            const int vrow = c >> 2;
            const int vcc  = (c & 3) ^ ((vrow >> 1) & 3);
            async_load16(Vt + vb + (size_t)vrow * SEQ + t0 + vcc * 8, &sV[bsel][cb * 8]);
        }
    };

    const int ntiles = 2 * sc + 2;
    stageKV(0, 0);
    __syncthreads();

    for (int tt = 0; tt < ntiles; tt++) {
        const int t0 = tt << 5;
        const int cur = tt & 1;
        if (tt + 1 < ntiles) stageKV((tt + 1) << 5, cur ^ 1);

        // S = Q·K^T
        f32x4 sacc[2];
        sacc[0] = (f32x4){0.f, 0.f, 0.f, 0.f};
        sacc[1] = (f32x4){0.f, 0.f, 0.f, 0.f};
#pragma unroll
        for (int ks = 0; ks < 4; ks++) {
#pragma unroll
            for (int jt = 0; jt < 2; jt++) {
                const int idx = (jt * 16 + l16) * 128 + (((ks * 4 + quad) ^ (l16 & 7)) * 8);
                const f16x8 kf = *reinterpret_cast<const f16x8*>(&sK[cur][idx]);
                sacc[jt] = __builtin_amdgcn_mfma_f32_16x16x32_f16(qf[ks], kf, sacc[jt], 0, 0, 0);
            }
        }

        // causal mask (only diagonal-region tiles)
        if (t0 >= s0) {
            const int rowg = s0 + wv * 16 + quad * 4;
#pragma unroll
            for (int jt = 0; jt < 2; jt++) {
                const int key = t0 + jt * 16 + l16;
#pragma unroll
                for (int r = 0; r < 4; r++)
                    if (key > rowg + r) sacc[jt][r] = -1e30f;
            }
        }

        // online softmax per reg (rows quad*4+reg; reduce over 16 l16 lanes)
        float alpha[4];
#pragma unroll
        for (int r = 0; r < 4; r++) {
            float mt = fmaxf(sacc[0][r], sacc[1][r]);
#pragma unroll
            for (int off = 8; off; off >>= 1) mt = fmaxf(mt, __shfl_xor(mt, off));
            const float mn = fmaxf(m_i[r], mt);
            alpha[r] = __expf(m_i[r] - mn);
            const float p0 = __expf(sacc[0][r] - mn);
            const float p1 = __expf(sacc[1][r] - mn);
            float ps = p0 + p1;
#pragma unroll
            for (int off = 8; off; off >>= 1) ps += __shfl_xor(ps, off);
            l_i[r] = l_i[r] * alpha[r] + ps;
            m_i[r] = mn;
            // write P: wave-private block, row = quad*4+r, key = jt*16+l16
            const int prow = quad * 4 + r;
            sP[wv * 512 + prow * 32 + 0 * 16 + l16] = f2h(p0);
            sP[wv * 512 + prow * 32 + 1 * 16 + l16] = f2h(p1);
        }

        // rescale O by alpha, then PV (sP same-wave RAW: in-order DS per wave)
#pragma unroll
        for (int dt = 0; dt < 8; dt++) {
#pragma unroll
            for (int r = 0; r < 4; r++) oacc[dt][r] *= alpha[r];
        }
        const f16x8 pf = *reinterpret_cast<const f16x8*>(&sP[wv * 512 + l16 * 32 + quad * 8]);
#pragma unroll
        for (int dt = 0; dt < 8; dt++) {
            const f16x8 vf = *reinterpret_cast<const f16x8*>(&sV[cur][(dt * 16 + l16) * 32 + qsw]);
            oacc[dt] = __builtin_amdgcn_mfma_f32_16x16x32_f16(pf, vf, oacc[dt], 0, 0, 0);
        }

        __syncthreads();   // drains next-tile loads; all reads of buf[cur] done
    }

    // final normalize + store (C-layout rows)
    float inv[4];
#pragma unroll
    for (int r = 0; r < 4; r++) inv[r] = 1.0f / l_i[r];
#pragma unroll
    for (int r = 0; r < 4; r++) {
        const size_t rowg = (size_t)(b * SEQ + s0 + wv * 16 + quad * 4 + r);
#pragma unroll
        for (int dt = 0; dt < 8; dt++)
            att[rowg * D_MODEL + h * HD + dt * 16 + l16] = f2h(oacc[dt][r] * inv[r]);
    }
}

// ---------------------------------------------------------------------------
extern "C" void kernel_launch(void* const* d_in, const int* in_sizes, int n_in,
                              void* d_out, int out_size, void* d_ws, size_t ws_size,
                              hipStream_t stream)
{
    (void)in_sizes; (void)n_in; (void)out_size; (void)ws_size;
    const float* x      = (const float*)d_in[0];
    const int*   wq_q   = (const int*)d_in[1];
    const float* wq_s   = (const float*)d_in[2];
    const float* bq     = (const float*)d_in[3];
    const int*   wk_q   = (const int*)d_in[4];
    const float* wk_s   = (const float*)d_in[5];
    const float* bk     = (const float*)d_in[6];
    const int*   wv_q   = (const int*)d_in[7];
    const float* wv_s   = (const float*)d_in[8];
    const float* bv     = (const float*)d_in[9];
    const int*   wo_q   = (const int*)d_in[10];
    const float* wo_s   = (const float*)d_in[11];
    const int*   gate_q = (const int*)d_in[12];
    const float* gate_s = (const float*)d_in[13];
    const int*   up_q   = (const int*)d_in[14];
    const float* up_s   = (const float*)d_in[15];
    const int*   down_q = (const int*)d_in[16];
    const float* down_s = (const float*)d_in[17];
    const float* w_in   = (const float*)d_in[18];
    const float* w_post = (const float*)d_in[19];
    const int*   offp   = (const int*)d_in[20];

    char* p = (char*)d_ws;
    auto alloc = [&](size_t bytes) {
        char* r = p;
        p += (bytes + 255) & ~(size_t)255;
        return r;
    };
    // persistent
    uint16_t* Wgu   = (uint16_t*)alloc((size_t)2 * D_FF * D_MODEL * 2);  // 46.1 MB
    uint16_t* Wdown = (uint16_t*)alloc((size_t)D_MODEL * D_FF * 2);      // 23.1 MB
    uint16_t* hbuf  = (uint16_t*)alloc((size_t)ROWS * D_MODEL * 2);      // h / h2
    float*    x2    = (float*)alloc((size_t)ROWS * D_MODEL * 4);
    // transient zone: Wqkv | Wo | qkv fp32  (aliased later)
    char* zone = alloc((size_t)N_QKV * D_MODEL * 2 +
                       (size_t)D_MODEL * D_MODEL * 2 +
                       (size_t)ROWS * N_QKV * 4 + 8192);
    uint16_t* Wqkv = (uint16_t*)zone;
    uint16_t* Wo   = Wqkv + (size_t)N_QKV * D_MODEL;
    float*    qkv  = (float*)(Wo + (size_t)D_MODEL * D_MODEL);
    // prep buffers alias Wqkv (dead after QKV GEMM): Q 8.39 + K 2.10 + V 2.10
    // = 12.58 MB = exactly sizeof(Wqkv).
    uint16_t* Qb = Wqkv;
    uint16_t* Kb = Qb + (size_t)BATCH * 16 * SEQ * HD;
    uint16_t* Vt = Kb + (size_t)BATCH * 4 * SEQ * HD;
    // attention output aliases qkv (dead after preps)
    uint16_t* att = (uint16_t*)qkv;
    // act aliases zone start (Wqkv/Wo/att all dead after O-proj); 23.1 MB
    uint16_t* act = (uint16_t*)zone;

    // all 7 dequants in ONE launch (static segment table)
    dequant_all_kernel<<<DQ_BLOCKS, 256, 0, stream>>>(
        wq_q, wq_s, wk_q, wk_s, wv_q, wv_s, wo_q, wo_s,
        gate_q, gate_s, up_q, up_s, down_q, down_s,
        Wqkv, Wo, Wgu, Wdown);

    rmsnorm_kernel<<<ROWS, 256, 0, stream>>>(x, w_in, hbuf);

    // QKV: 128x128 tiles -> 16*24 = 384 blocks; bias fused
    gemm_f16_m128_kernel<<<(ROWS / 128) * (N_QKV / 128), 256, 0, stream>>>(
        hbuf, Wqkv, bq, bk, bv, nullptr, qkv, ROWS, N_QKV, D_MODEL);

    rope_qk_kernel<<<ROPE_THREADS / 256, 256, 0, stream>>>(qkv, offp, Qb, Kb);
    prep_v_kernel<<<BATCH * 4 * (SEQ / 64), 256, 0, stream>>>(qkv, Vt);

    attn_kernel<<<BATCH * HEADS * (SEQ / 64), 256, 0, stream>>>(Qb, Kb, Vt, att);

    // O-proj: 16*16 = 256 blocks, resid fused
    gemm_f16_m128_kernel<<<(ROWS / 128) * (D_MODEL / 128), 256, 0, stream>>>(
        att, Wo, nullptr, nullptr, nullptr, x, x2, ROWS, D_MODEL, D_MODEL);

    rmsnorm_kernel<<<ROWS, 256, 0, stream>>>(x2, w_post, hbuf);

    // GU: 128x128 tiles, 1408 blocks
    gemm_f16_glu_kernel<<<(ROWS / 128) * (2 * D_FF / 128), 256, 0, stream>>>(
        hbuf, Wgu, act, ROWS, 2 * D_FF, D_MODEL);

    // down: 16*16 = 256 blocks, resid (x2) fused, writes final output
    gemm_f16_m128_kernel<<<(ROWS / 128) * (D_MODEL / 128), 256, 0, stream>>>(
        act, Wdown, nullptr, nullptr, nullptr, x2, (float*)d_out, ROWS, D_MODEL, D_FF);
}

// Round 7
// 540.310 us; speedup vs baseline: 1.0435x; 1.0435x over previous
//
#include <hip/hip_runtime.h>
#include <cstdint>
#include <cstddef>

#define DEV __device__ __forceinline__

typedef _Float16 f16x8 __attribute__((ext_vector_type(8)));
typedef float f32x4 __attribute__((ext_vector_type(4)));

static constexpr int D_MODEL = 2048;
static constexpr int D_FF    = 5632;
static constexpr int N_QKV   = 3072;   // 2048 q + 512 k + 512 v
static constexpr int SEQ     = 1024;
static constexpr int BATCH   = 2;
static constexpr int ROWS    = BATCH * SEQ;  // 2048
static constexpr int HEADS   = 16;
static constexpr int HD      = 128;

DEV uint16_t f2h(float f) {
    return __builtin_bit_cast(uint16_t, (_Float16)f);   // RTNE, 2^-12 RMS rel err
}

// async global->LDS, 16B/lane; lds ptr must be wave-uniform (HW adds lane*16)
DEV void async_load16(const void* g, void* lds) {
    __builtin_amdgcn_global_load_lds(
        reinterpret_cast<__attribute__((address_space(1))) void*>(
            reinterpret_cast<uintptr_t>(g)),
        reinterpret_cast<__attribute__((address_space(3))) void*>(
            static_cast<uint32_t>(reinterpret_cast<uintptr_t>(lds))),
        16, 0, 0);
}

// ---------------------------------------------------------------------------
// Merged dequant: ALL 7 weight tensors in one launch (static segment table).
// w = q*s (fp32) -> fp16. mode 0: orow=row; 1: gate interleave; 2: up.
// ---------------------------------------------------------------------------
static constexpr int DQ_BLOCKS = 44032;

__global__ __launch_bounds__(256)
void dequant_all_kernel(const int* __restrict__ wq_q, const float* __restrict__ wq_s,
                        const int* __restrict__ wk_q, const float* __restrict__ wk_s,
                        const int* __restrict__ wv_q, const float* __restrict__ wv_s,
                        const int* __restrict__ wo_q, const float* __restrict__ wo_s,
                        const int* __restrict__ gate_q, const float* __restrict__ gate_s,
                        const int* __restrict__ up_q, const float* __restrict__ up_s,
                        const int* __restrict__ down_q, const float* __restrict__ down_s,
                        uint16_t* __restrict__ Wqkv, uint16_t* __restrict__ Wo,
                        uint16_t* __restrict__ Wgu, uint16_t* __restrict__ Wdown)
{
    const int bid = blockIdx.x;
    const int* q; const float* s; uint16_t* out; int I, mode, seg0;
    if (bid < 4096)        { q = wq_q;   s = wq_s;   out = Wqkv;                      I = 2048; mode = 0; seg0 = 0; }
    else if (bid < 5120)   { q = wk_q;   s = wk_s;   out = Wqkv + 2048 * 2048;        I = 2048; mode = 0; seg0 = 4096; }
    else if (bid < 6144)   { q = wv_q;   s = wv_s;   out = Wqkv + 2560 * 2048;        I = 2048; mode = 0; seg0 = 5120; }
    else if (bid < 10240)  { q = wo_q;   s = wo_s;   out = Wo;                        I = 2048; mode = 0; seg0 = 6144; }
    else if (bid < 21504)  { q = gate_q; s = gate_s; out = Wgu;                       I = 2048; mode = 1; seg0 = 10240; }
    else if (bid < 32768)  { q = up_q;   s = up_s;   out = Wgu;                       I = 2048; mode = 2; seg0 = 21504; }
    else                   { q = down_q; s = down_s; out = Wdown;                     I = 5632; mode = 0; seg0 = 32768; }

    const int idx = (bid - seg0) * 256 + threadIdx.x;
    const int e = idx * 4;
    const int row = e / I;
    const int i = e - row * I;
    const int4 qv = *reinterpret_cast<const int4*>(&q[e]);
    const float scf = s[row * (I >> 6) + (i >> 6)];
    int orow = row;
    if (mode == 1) orow = ((row >> 4) << 5) + (row & 15);
    else if (mode == 2) orow = ((row >> 4) << 5) + (row & 15) + 16;
    uint16_t h[4];
    h[0] = f2h((float)qv.x * scf);
    h[1] = f2h((float)qv.y * scf);
    h[2] = f2h((float)qv.z * scf);
    h[3] = f2h((float)qv.w * scf);
    uint2 pk;
    pk.x = (uint32_t)h[0] | ((uint32_t)h[1] << 16);
    pk.y = (uint32_t)h[2] | ((uint32_t)h[3] << 16);
    *reinterpret_cast<uint2*>(&out[(size_t)orow * I + i]) = pk;
}

// ---------------------------------------------------------------------------
// RMSNorm (fp32 in) -> fp16. One row (2048) per block of 256.
// ---------------------------------------------------------------------------
__global__ __launch_bounds__(256)
void rmsnorm_kernel(const float* __restrict__ x, const float* __restrict__ wln,
                    uint16_t* __restrict__ out)
{
    __shared__ float red[4];
    const int row = blockIdx.x;
    const int tid = threadIdx.x;
    const float* xr = x + (size_t)row * D_MODEL;
    const float4 v0 = *reinterpret_cast<const float4*>(&xr[tid * 8]);
    const float4 v1 = *reinterpret_cast<const float4*>(&xr[tid * 8 + 4]);
    float ss = v0.x*v0.x + v0.y*v0.y + v0.z*v0.z + v0.w*v0.w
             + v1.x*v1.x + v1.y*v1.y + v1.z*v1.z + v1.w*v1.w;
#pragma unroll
    for (int off = 32; off; off >>= 1) ss += __shfl_xor(ss, off);
    if ((tid & 63) == 0) red[tid >> 6] = ss;
    __syncthreads();
    const float rms = rsqrtf((red[0] + red[1] + red[2] + red[3]) * (1.0f / D_MODEL) + 1e-6f);
    const int cb = tid * 8;
    const size_t base = (size_t)row * D_MODEL + cb;
    const float vals[8] = {v0.x, v0.y, v0.z, v0.w, v1.x, v1.y, v1.z, v1.w};
#pragma unroll
    for (int k = 0; k < 8; k += 2) {
        const uint16_t h0 = f2h(vals[k] * rms * wln[cb + k]);
        const uint16_t h1 = f2h(vals[k + 1] * rms * wln[cb + k + 1]);
        *reinterpret_cast<uint32_t*>(&out[base + k]) = (uint32_t)h0 | ((uint32_t)h1 << 16);
    }
}

// ---------------------------------------------------------------------------
// fp16 GEMM, 128x128 tile (fused SwiGLU epilogue, gate/up interleaved W).
// Round-6 verified: 875 TF = at the 128^2/2-barrier structure ceiling.
// Row-major block map (NO xcd remap — round-5/6 A/B: remap costs +4-9 us).
// BK=64, A+B double-buffered LDS, ONE barrier per K-tile. Both-sides swizzle:
// granule p at row r holds logical p^(r&7); ds_read applies same XOR.
// ---------------------------------------------------------------------------
__global__ __launch_bounds__(256)
void gemm_f16_glu_kernel(const uint16_t* __restrict__ A, const uint16_t* __restrict__ W,
                         uint16_t* __restrict__ outh, int M, int N, int K)
{
    __shared__ uint16_t sA[2][128 * 64];
    __shared__ uint16_t sB[2][128 * 64];

    const int tid  = threadIdx.x;
    const int lane = tid & 63;
    const int wv   = tid >> 6;
    const int wm   = wv >> 1;
    const int wn   = wv & 1;
    const int quad = lane >> 4;
    const int l16  = lane & 15;

    const int nBn = N >> 7;
    const int bm  = blockIdx.x / nBn;
    const int bn  = blockIdx.x - bm * nBn;
    const int m0  = bm << 7;
    const int n0  = bn << 7;

    f32x4 acc[4][4];
#pragma unroll
    for (int i = 0; i < 4; i++)
#pragma unroll
        for (int j = 0; j < 4; j++)
            acc[i][j] = (f32x4){0.f, 0.f, 0.f, 0.f};

    const uint16_t* Ab = A + (size_t)m0 * K;
    const uint16_t* Wb = W + (size_t)n0 * K;

    auto stage = [&](int kt, int bsel) {
#pragma unroll
        for (int p = 0; p < 4; p++) {
            const int cb = p * 256 + wv * 64;          // wave-uniform chunk base
            const int c  = cb + lane;
            const int row = c >> 3;
            const int g   = (c & 7) ^ (row & 7);       // pre-swizzled source
            const size_t goff = (size_t)row * K + kt + g * 8;
            async_load16(Ab + goff, &sA[bsel][cb * 8]);
            async_load16(Wb + goff, &sB[bsel][cb * 8]);
        }
    };

    stage(0, 0);
    __syncthreads();

    const int nKt = K >> 6;
    for (int t = 0; t < nKt; t++) {
        const int cur = t & 1;
        if (t + 1 < nKt) stage((t + 1) << 6, cur ^ 1);
        const uint16_t* sAc = sA[cur];
        const uint16_t* sBc = sB[cur];
#pragma unroll
        for (int kk = 0; kk < 2; kk++) {
            const int gsw = ((kk * 4 + quad) ^ (l16 & 7)) * 8;   // swizzled read granule
            f16x8 bfv[4];
#pragma unroll
            for (int j = 0; j < 4; j++)
                bfv[j] = *reinterpret_cast<const f16x8*>(
                    &sBc[(wn * 64 + j * 16 + l16) * 64 + gsw]);
#pragma unroll
            for (int i = 0; i < 4; i++) {
                const f16x8 af = *reinterpret_cast<const f16x8*>(
                    &sAc[(wm * 64 + i * 16 + l16) * 64 + gsw]);
#pragma unroll
                for (int j = 0; j < 4; j++)
                    acc[i][j] = __builtin_amdgcn_mfma_f32_16x16x32_f16(af, bfv[j], acc[i][j], 0, 0, 0);
            }
        }
        __syncthreads();   // drains vmcnt (t+1 loads) + syncs reads of buf[cur]
    }

    // SwiGLU: j even = gate, j odd = up of same 16-col group.
    const int NH = N >> 1;
#pragma unroll
    for (int i = 0; i < 4; i++) {
        const int rowb = m0 + wm * 64 + i * 16 + quad * 4;
#pragma unroll
        for (int r = 0; r < 4; r++) {
            const size_t rr = (size_t)(rowb + r);
#pragma unroll
            for (int pjt = 0; pjt < 2; pjt++) {
                const float g = acc[i][2 * pjt][r];
                const float u = acc[i][2 * pjt + 1][r];
                const float a = (g / (1.0f + __expf(-g))) * u;
                const int cc = (n0 >> 1) + wn * 32 + pjt * 16 + l16;
                outh[rr * NH + cc] = f2h(a);
            }
        }
    }
}

// ---------------------------------------------------------------------------
// fp16 GEMM, 64x128 tile (fp32 out, +QKV-bias select / +resid). Round-3
// verified kernel (no remap): BK=64, A+B dbuf, one barrier per K-tile.
// 48 KB LDS -> 3 blocks/CU; round-6 A/B showed this inter-block overlap beats
// the 128-tile's read economy at 1 block/CU for the square GEMMs.
// 4 waves side-by-side along N: wave = rows 0..63 x cols wv*32..+31, acc[4][2].
// ---------------------------------------------------------------------------
__global__ __launch_bounds__(256)
void gemm_f16_m64_kernel(const uint16_t* __restrict__ A, const uint16_t* __restrict__ W,
                         const float* __restrict__ bq, const float* __restrict__ bk,
                         const float* __restrict__ bv, const float* __restrict__ resid,
                         float* __restrict__ outf, int M, int N, int K)
{
    __shared__ uint16_t sA[2][64 * 64];
    __shared__ uint16_t sB[2][128 * 64];

    const int tid  = threadIdx.x;
    const int lane = tid & 63;
    const int wv   = tid >> 6;
    const int quad = lane >> 4;
    const int l16  = lane & 15;

    const int nBn = N >> 7;
    const int bm  = blockIdx.x / nBn;
    const int bn  = blockIdx.x - bm * nBn;
    const int m0  = bm << 6;
    const int n0  = bn << 7;

    f32x4 acc[4][2];
#pragma unroll
    for (int i = 0; i < 4; i++)
#pragma unroll
        for (int j = 0; j < 2; j++)
            acc[i][j] = (f32x4){0.f, 0.f, 0.f, 0.f};

    const uint16_t* Ab = A + (size_t)m0 * K;
    const uint16_t* Wb = W + (size_t)n0 * K;

    auto stage = [&](int kt, int bsel) {
#pragma unroll
        for (int p = 0; p < 2; p++) {   // A tile: 512 chunks
            const int cb = p * 256 + wv * 64;
            const int c  = cb + lane;
            const int row = c >> 3;
            const int g   = (c & 7) ^ (row & 7);
            async_load16(Ab + (size_t)row * K + kt + g * 8, &sA[bsel][cb * 8]);
        }
#pragma unroll
        for (int p = 0; p < 4; p++) {   // B tile: 1024 chunks
            const int cb = p * 256 + wv * 64;
            const int c  = cb + lane;
            const int row = c >> 3;
            const int g   = (c & 7) ^ (row & 7);
            async_load16(Wb + (size_t)row * K + kt + g * 8, &sB[bsel][cb * 8]);
        }
    };

    stage(0, 0);
    __syncthreads();

    const int nKt = K >> 6;
    for (int t = 0; t < nKt; t++) {
        const int cur = t & 1;
        if (t + 1 < nKt) stage((t + 1) << 6, cur ^ 1);
        const uint16_t* sAc = sA[cur];
        const uint16_t* sBc = sB[cur];
#pragma unroll
        for (int kk = 0; kk < 2; kk++) {
            const int gsw = ((kk * 4 + quad) ^ (l16 & 7)) * 8;
            f16x8 bfv[2];
#pragma unroll
            for (int j = 0; j < 2; j++)
                bfv[j] = *reinterpret_cast<const f16x8*>(
                    &sBc[(wv * 32 + j * 16 + l16) * 64 + gsw]);
#pragma unroll
            for (int i = 0; i < 4; i++) {
                const f16x8 af = *reinterpret_cast<const f16x8*>(
                    &sAc[(i * 16 + l16) * 64 + gsw]);
#pragma unroll
                for (int j = 0; j < 2; j++)
                    acc[i][j] = __builtin_amdgcn_mfma_f32_16x16x32_f16(af, bfv[j], acc[i][j], 0, 0, 0);
            }
        }
        __syncthreads();
    }

    // epilogue: C row = quad*4+reg, col = lane&15 (m89-verified, dtype-indep)
#pragma unroll
    for (int i = 0; i < 4; i++) {
        const int rowb = m0 + i * 16 + quad * 4;
#pragma unroll
        for (int r = 0; r < 4; r++) {
            const size_t rr = (size_t)(rowb + r);
#pragma unroll
            for (int j = 0; j < 2; j++) {
                const int cc = n0 + wv * 32 + j * 16 + l16;
                float v = acc[i][j][r];
                if (bq) {   // QKV bias concat (boundaries are layout consts)
                    float bb;
                    if (cc < 2048)      bb = bq[cc];
                    else if (cc < 2560) bb = bk[cc - 2048];
                    else                bb = bv[cc - 2560];
                    v += bb;
                }
                if (resid) v += resid[rr * N + cc];
                outf[rr * N + cc] = v;
            }
        }
    }
}

// ---------------------------------------------------------------------------
// Merged RoPE prep: Q then K in one launch. Fast trig:
//   freq = 1e6^(-d/64) = exp2(-d * log2(1e6)/64)  -> 1 v_exp_f32
//   __sincosf -> v_sin/v_cos (hw fract range reduction; arg <= ~6.4e3 ->
//   error ~1e-4, below the fp16 pipeline's 5e-4 quantization step)
// ---------------------------------------------------------------------------
static constexpr int ROPE_Q_THREADS = ROWS * 16 * 64;   // 2,097,152
static constexpr int ROPE_THREADS   = ROPE_Q_THREADS + ROWS * 4 * 64;
static constexpr float LOG2_1E6_OVER_64 = 0.31143075889910283f;   // log2(1e6)/64

__global__ __launch_bounds__(256)
void rope_qk_kernel(const float* __restrict__ qkv, const int* __restrict__ offp,
                    uint16_t* __restrict__ Qb, uint16_t* __restrict__ Kb)
{
    const int gidx = blockIdx.x * 256 + threadIdx.x;
    if (gidx < ROPE_Q_THREADS) {
        const int idx = gidx;
        const int d   = idx & 63;
        const int h   = (idx >> 6) & 15;
        const int row = idx >> 10;
        const int b   = row >> 10;
        const int s   = row & (SEQ - 1);
        const float pos  = (float)(s + *offp);
        const float freq = exp2f(-(float)d * LOG2_1E6_OVER_64);
        float sn, cs;
        __sincosf(pos * freq, &sn, &cs);
        const size_t gb = (size_t)row * N_QKV + h * HD + d;
        const float x1 = qkv[gb];
        const float x2 = qkv[gb + 64];
        const float qscale = 0.08838834764831845f;   // 1/sqrt(128)
        const size_t ob = ((size_t)(b * 16 + h) * SEQ + s) * HD + d;
        Qb[ob]      = f2h((x1 * cs - x2 * sn) * qscale);
        Qb[ob + 64] = f2h((x2 * cs + x1 * sn) * qscale);
    } else {
        const int idx = gidx - ROPE_Q_THREADS;
        const int d   = idx & 63;
        const int kvh = (idx >> 6) & 3;
        const int row = idx >> 8;
        const int b   = row >> 10;
        const int s   = row & (SEQ - 1);
        const float pos  = (float)(s + *offp);
        const float freq = exp2f(-(float)d * LOG2_1E6_OVER_64);
        float sn, cs;
        __sincosf(pos * freq, &sn, &cs);
        const size_t gb = (size_t)row * N_QKV + 2048 + kvh * HD + d;
        const float x1 = qkv[gb];
        const float x2 = qkv[gb + 64];
        const size_t ob = ((size_t)(b * 4 + kvh) * SEQ + s) * HD + d;
        Kb[ob]      = f2h(x1 * cs - x2 * sn);
        Kb[ob + 64] = f2h(x2 * cs + x1 * sn);
    }
}

// V transpose prep: qkv fp32 -> fp16 V^T [(b*4+kvh)*128+dim][1024 keys].
__global__ __launch_bounds__(256)
void prep_v_kernel(const float* __restrict__ qkv, uint16_t* __restrict__ Vt)
{
    __shared__ uint16_t sh[128 * 72];
    const int tid = threadIdx.x;
    const int sc  = blockIdx.x & 15;     // 16 chunks of 64 keys
    const int bk  = blockIdx.x >> 4;     // b*4+kvh
    const int b   = bk >> 2, kvh = bk & 3;
#pragma unroll
    for (int p = 0; p < 8; p++) {
        const int q4 = p * 256 + tid;    // 2048 float4s: 64 rows x 32
        const int sloc = q4 >> 5, d4 = (q4 & 31) * 4;
        const float4 v = *reinterpret_cast<const float4*>(
            &qkv[(size_t)(b * SEQ + sc * 64 + sloc) * N_QKV + 2560 + kvh * HD + d4]);
        sh[(d4 + 0) * 72 + sloc] = f2h(v.x);
        sh[(d4 + 1) * 72 + sloc] = f2h(v.y);
        sh[(d4 + 2) * 72 + sloc] = f2h(v.z);
        sh[(d4 + 3) * 72 + sloc] = f2h(v.w);
    }
    __syncthreads();
    const int d = tid >> 1, half = tid & 1;
    const size_t ob = ((size_t)(bk * 128 + d)) * SEQ + sc * 64 + half * 32;
    const uint16_t* srh = &sh[d * 72 + half * 32];
#pragma unroll
    for (int k = 0; k < 4; k++)
        *reinterpret_cast<uint4*>(&Vt[ob + k * 8]) =
            *reinterpret_cast<const uint4*>(&srh[k * 8]);
}

// ---------------------------------------------------------------------------
// MFMA fp16 flash attention (round-3 verified). Block = 64 Q rows of one
// (b,h); 4 waves x 16 rows. 32-key tiles, double-buffered K/V staging, ONE
// barrier per tile. sP is wave-private. K granule^row swizzle; V^T
// granule^(row>>1) swizzle.
// ---------------------------------------------------------------------------
__global__ __launch_bounds__(256)
void attn_kernel(const uint16_t* __restrict__ Qb, const uint16_t* __restrict__ Kb,
                 const uint16_t* __restrict__ Vt, uint16_t* __restrict__ att)
{
    __shared__ uint16_t sK[2][32 * 128];
    __shared__ uint16_t sV[2][128 * 32];
    __shared__ uint16_t sP[4 * 16 * 32];

    const int tid  = threadIdx.x;
    const int lane = tid & 63;
    const int wv   = tid >> 6;
    const int quad = lane >> 4;
    const int l16  = lane & 15;
    const int qsw  = (quad ^ ((l16 >> 1) & 3)) * 8;   // swizzled V read granule

    const int bi  = blockIdx.x;
    const int sc  = 15 - (bi >> 5);      // big Q-tiles dispatched first
    const int bh  = bi & 31;
    const int b   = bh >> 4;
    const int h   = bh & 15;
    const int kvh = h >> 2;
    const int s0  = sc << 6;

    // Q fragments (A-layout) straight from global, once.
    f16x8 qf[4];
    {
        const size_t qb = ((size_t)(b * 16 + h) * SEQ + s0 + wv * 16 + l16) * HD;
#pragma unroll
        for (int ks = 0; ks < 4; ks++)
            qf[ks] = *reinterpret_cast<const f16x8*>(&Qb[qb + ks * 32 + quad * 8]);
    }

    float m_i[4], l_i[4];
#pragma unroll
    for (int r = 0; r < 4; r++) { m_i[r] = -1e30f; l_i[r] = 0.f; }
    f32x4 oacc[8];
#pragma unroll
    for (int dt = 0; dt < 8; dt++) oacc[dt] = (f32x4){0.f, 0.f, 0.f, 0.f};

    const size_t kb = (size_t)(b * 4 + kvh) * SEQ * HD;        // K base (elems)
    const size_t vb = (size_t)(b * 4 + kvh) * HD * SEQ;        // V^T base

    auto stageKV = [&](int t0, int bsel) {
#pragma unroll
        for (int p = 0; p < 2; p++) {
            const int cb = p * 256 + wv * 64;
            const int c  = cb + lane;
            const int krow = c >> 4;
            const int kcc  = (c & 15) ^ (krow & 7);
            async_load16(Kb + kb + (size_t)(t0 + krow) * HD + kcc * 8, &sK[bsel][cb * 8]);
            const int vrow = c >> 2;
            const int vcc  = (c & 3) ^ ((vrow >> 1) & 3);
            async_load16(Vt + vb + (size_t)vrow * SEQ + t0 + vcc * 8, &sV[bsel][cb * 8]);
        }
    };

    const int ntiles = 2 * sc + 2;
    stageKV(0, 0);
    __syncthreads();

    for (int tt = 0; tt < ntiles; tt++) {
        const int t0 = tt << 5;
        const int cur = tt & 1;
        if (tt + 1 < ntiles) stageKV((tt + 1) << 5, cur ^ 1);

        // S = Q·K^T
        f32x4 sacc[2];
        sacc[0] = (f32x4){0.f, 0.f, 0.f, 0.f};
        sacc[1] = (f32x4){0.f, 0.f, 0.f, 0.f};
#pragma unroll
        for (int ks = 0; ks < 4; ks++) {
#pragma unroll
            for (int jt = 0; jt < 2; jt++) {
                const int idx = (jt * 16 + l16) * 128 + (((ks * 4 + quad) ^ (l16 & 7)) * 8);
                const f16x8 kf = *reinterpret_cast<const f16x8*>(&sK[cur][idx]);
                sacc[jt] = __builtin_amdgcn_mfma_f32_16x16x32_f16(qf[ks], kf, sacc[jt], 0, 0, 0);
            }
        }

        // causal mask (only diagonal-region tiles)
        if (t0 >= s0) {
            const int rowg = s0 + wv * 16 + quad * 4;
#pragma unroll
            for (int jt = 0; jt < 2; jt++) {
                const int key = t0 + jt * 16 + l16;
#pragma unroll
                for (int r = 0; r < 4; r++)
                    if (key > rowg + r) sacc[jt][r] = -1e30f;
            }
        }

        // online softmax per reg (rows quad*4+reg; reduce over 16 l16 lanes)
        float alpha[4];
#pragma unroll
        for (int r = 0; r < 4; r++) {
            float mt = fmaxf(sacc[0][r], sacc[1][r]);
#pragma unroll
            for (int off = 8; off; off >>= 1) mt = fmaxf(mt, __shfl_xor(mt, off));
            const float mn = fmaxf(m_i[r], mt);
            alpha[r] = __expf(m_i[r] - mn);
            const float p0 = __expf(sacc[0][r] - mn);
            const float p1 = __expf(sacc[1][r] - mn);
            float ps = p0 + p1;
#pragma unroll
            for (int off = 8; off; off >>= 1) ps += __shfl_xor(ps, off);
            l_i[r] = l_i[r] * alpha[r] + ps;
            m_i[r] = mn;
            // write P: wave-private block, row = quad*4+r, key = jt*16+l16
            const int prow = quad * 4 + r;
            sP[wv * 512 + prow * 32 + 0 * 16 + l16] = f2h(p0);
            sP[wv * 512 + prow * 32 + 1 * 16 + l16] = f2h(p1);
        }

        // rescale O by alpha, then PV (sP same-wave RAW: in-order DS per wave)
#pragma unroll
        for (int dt = 0; dt < 8; dt++) {
#pragma unroll
            for (int r = 0; r < 4; r++) oacc[dt][r] *= alpha[r];
        }
        const f16x8 pf = *reinterpret_cast<const f16x8*>(&sP[wv * 512 + l16 * 32 + quad * 8]);
#pragma unroll
        for (int dt = 0; dt < 8; dt++) {
            const f16x8 vf = *reinterpret_cast<const f16x8*>(&sV[cur][(dt * 16 + l16) * 32 + qsw]);
            oacc[dt] = __builtin_amdgcn_mfma_f32_16x16x32_f16(pf, vf, oacc[dt], 0, 0, 0);
        }

        __syncthreads();   // drains next-tile loads; all reads of buf[cur] done
    }

    // final normalize + store (C-layout rows)
    float inv[4];
#pragma unroll
    for (int r = 0; r < 4; r++) inv[r] = 1.0f / l_i[r];
#pragma unroll
    for (int r = 0; r < 4; r++) {
        const size_t rowg = (size_t)(b * SEQ + s0 + wv * 16 + quad * 4 + r);
#pragma unroll
        for (int dt = 0; dt < 8; dt++)
            att[rowg * D_MODEL + h * HD + dt * 16 + l16] = f2h(oacc[dt][r] * inv[r]);
    }
}

// ---------------------------------------------------------------------------
extern "C" void kernel_launch(void* const* d_in, const int* in_sizes, int n_in,
                              void* d_out, int out_size, void* d_ws, size_t ws_size,
                              hipStream_t stream)
{
    (void)in_sizes; (void)n_in; (void)out_size; (void)ws_size;
    const float* x      = (const float*)d_in[0];
    const int*   wq_q   = (const int*)d_in[1];
    const float* wq_s   = (const float*)d_in[2];
    const float* bq     = (const float*)d_in[3];
    const int*   wk_q   = (const int*)d_in[4];
    const float* wk_s   = (const float*)d_in[5];
    const float* bk     = (const float*)d_in[6];
    const int*   wv_q   = (const int*)d_in[7];
    const float* wv_s   = (const float*)d_in[8];
    const float* bv     = (const float*)d_in[9];
    const int*   wo_q   = (const int*)d_in[10];
    const float* wo_s   = (const float*)d_in[11];
    const int*   gate_q = (const int*)d_in[12];
    const float* gate_s = (const float*)d_in[13];
    const int*   up_q   = (const int*)d_in[14];
    const float* up_s   = (const float*)d_in[15];
    const int*   down_q = (const int*)d_in[16];
    const float* down_s = (const float*)d_in[17];
    const float* w_in   = (const float*)d_in[18];
    const float* w_post = (const float*)d_in[19];
    const int*   offp   = (const int*)d_in[20];

    char* p = (char*)d_ws;
    auto alloc = [&](size_t bytes) {
        char* r = p;
        p += (bytes + 255) & ~(size_t)255;
        return r;
    };
    // persistent
    uint16_t* Wgu   = (uint16_t*)alloc((size_t)2 * D_FF * D_MODEL * 2);  // 46.1 MB
    uint16_t* Wdown = (uint16_t*)alloc((size_t)D_MODEL * D_FF * 2);      // 23.1 MB
    uint16_t* hbuf  = (uint16_t*)alloc((size_t)ROWS * D_MODEL * 2);      // h / h2
    float*    x2    = (float*)alloc((size_t)ROWS * D_MODEL * 4);
    // transient zone: Wqkv | Wo | qkv fp32  (aliased later)
    char* zone = alloc((size_t)N_QKV * D_MODEL * 2 +
                       (size_t)D_MODEL * D_MODEL * 2 +
                       (size_t)ROWS * N_QKV * 4 + 8192);
    uint16_t* Wqkv = (uint16_t*)zone;
    uint16_t* Wo   = Wqkv + (size_t)N_QKV * D_MODEL;
    float*    qkv  = (float*)(Wo + (size_t)D_MODEL * D_MODEL);
    // prep buffers alias Wqkv (dead after QKV GEMM): Q 8.39 + K 2.10 + V 2.10
    // = 12.58 MB = exactly sizeof(Wqkv).
    uint16_t* Qb = Wqkv;
    uint16_t* Kb = Qb + (size_t)BATCH * 16 * SEQ * HD;
    uint16_t* Vt = Kb + (size_t)BATCH * 4 * SEQ * HD;
    // attention output aliases qkv (dead after preps)
    uint16_t* att = (uint16_t*)qkv;
    // act aliases zone start (Wqkv/Wo/att all dead after O-proj); 23.1 MB
    uint16_t* act = (uint16_t*)zone;

    // all 7 dequants in ONE launch (static segment table)
    dequant_all_kernel<<<DQ_BLOCKS, 256, 0, stream>>>(
        wq_q, wq_s, wk_q, wk_s, wv_q, wv_s, wo_q, wo_s,
        gate_q, gate_s, up_q, up_s, down_q, down_s,
        Wqkv, Wo, Wgu, Wdown);

    rmsnorm_kernel<<<ROWS, 256, 0, stream>>>(x, w_in, hbuf);

    // QKV: 64x128 tiles -> 768 blocks (3/CU); bias fused
    gemm_f16_m64_kernel<<<(ROWS / 64) * (N_QKV / 128), 256, 0, stream>>>(
        hbuf, Wqkv, bq, bk, bv, nullptr, qkv, ROWS, N_QKV, D_MODEL);

    rope_qk_kernel<<<ROPE_THREADS / 256, 256, 0, stream>>>(qkv, offp, Qb, Kb);
    prep_v_kernel<<<BATCH * 4 * (SEQ / 64), 256, 0, stream>>>(qkv, Vt);

    attn_kernel<<<BATCH * HEADS * (SEQ / 64), 256, 0, stream>>>(Qb, Kb, Vt, att);

    // O-proj: 512 blocks (3/CU), resid fused
    gemm_f16_m64_kernel<<<(ROWS / 64) * (D_MODEL / 128), 256, 0, stream>>>(
        att, Wo, nullptr, nullptr, nullptr, x, x2, ROWS, D_MODEL, D_MODEL);

    rmsnorm_kernel<<<ROWS, 256, 0, stream>>>(x2, w_post, hbuf);

    // GU: 128x128 tiles, 1408 blocks (at structure ceiling, 875 TF)
    gemm_f16_glu_kernel<<<(ROWS / 128) * (2 * D_FF / 128), 256, 0, stream>>>(
        hbuf, Wgu, act, ROWS, 2 * D_FF, D_MODEL);

    // down: 512 blocks (3/CU), resid (x2) fused, writes final output
    gemm_f16_m64_kernel<<<(ROWS / 64) * (D_MODEL / 128), 256, 0, stream>>>(
        act, Wdown, nullptr, nullptr, nullptr, x2, (float*)d_out, ROWS, D_MODEL, D_FF);
}

// Round 8
// 516.121 us; speedup vs baseline: 1.0924x; 1.0469x over previous
//
#include <hip/hip_runtime.h>
#include <cstdint>
#include <cstddef>

#define DEV __device__ __forceinline__

typedef _Float16 f16x8 __attribute__((ext_vector_type(8)));
typedef float f32x4 __attribute__((ext_vector_type(4)));

static constexpr int D_MODEL = 2048;
static constexpr int D_FF    = 5632;
static constexpr int N_QKV   = 3072;   // 2048 q + 512 k + 512 v
static constexpr int SEQ     = 1024;
static constexpr int BATCH   = 2;
static constexpr int ROWS    = BATCH * SEQ;  // 2048
static constexpr int HEADS   = 16;
static constexpr int HD      = 128;

DEV uint16_t f2h(float f) {
    return __builtin_bit_cast(uint16_t, (_Float16)f);   // RTNE, 2^-12 RMS rel err
}

// async global->LDS, 16B/lane; lds ptr must be wave-uniform (HW adds lane*16)
DEV void async_load16(const void* g, void* lds) {
    __builtin_amdgcn_global_load_lds(
        reinterpret_cast<__attribute__((address_space(1))) void*>(
            reinterpret_cast<uintptr_t>(g)),
        reinterpret_cast<__attribute__((address_space(3))) void*>(
            static_cast<uint32_t>(reinterpret_cast<uintptr_t>(lds))),
        16, 0, 0);
}

// ---------------------------------------------------------------------------
// Dequant block body: 256 threads x 4 elems. w = q*s -> fp16.
// mode 0: orow=row; 1: gate interleave; 2: up interleave.
// ---------------------------------------------------------------------------
DEV void dq_body(const int* __restrict__ q, const float* __restrict__ s,
                 uint16_t* __restrict__ out, int I, int mode, int idx)
{
    const int e = idx * 4;
    const int row = e / I;
    const int i = e - row * I;
    const int4 qv = *reinterpret_cast<const int4*>(&q[e]);
    const float scf = s[row * (I >> 6) + (i >> 6)];
    int orow = row;
    if (mode == 1) orow = ((row >> 4) << 5) + (row & 15);
    else if (mode == 2) orow = ((row >> 4) << 5) + (row & 15) + 16;
    uint16_t h[4];
    h[0] = f2h((float)qv.x * scf);
    h[1] = f2h((float)qv.y * scf);
    h[2] = f2h((float)qv.z * scf);
    h[3] = f2h((float)qv.w * scf);
    uint2 pk;
    pk.x = (uint32_t)h[0] | ((uint32_t)h[1] << 16);
    pk.y = (uint32_t)h[2] | ((uint32_t)h[3] << 16);
    *reinterpret_cast<uint2*>(&out[(size_t)orow * I + i]) = pk;
}

// ---------------------------------------------------------------------------
// Mixed launch 1: rmsnorm (blocks [0,2048)) || dequant Wqkv+Wo (blocks
// [2048,12288)). Both only needed before the QKV GEMM; independent of each
// other -> co-scheduled to overlap rmsnorm's reduce with dequant's BW.
// ---------------------------------------------------------------------------
__global__ __launch_bounds__(256)
void norm_dqA_kernel(const float* __restrict__ x, const float* __restrict__ wln,
                     uint16_t* __restrict__ outh,
                     const int* __restrict__ wq_q, const float* __restrict__ wq_s,
                     const int* __restrict__ wk_q, const float* __restrict__ wk_s,
                     const int* __restrict__ wv_q, const float* __restrict__ wv_s,
                     const int* __restrict__ wo_q, const float* __restrict__ wo_s,
                     uint16_t* __restrict__ Wqkv, uint16_t* __restrict__ Wo)
{
    __shared__ float red[4];
    const int bid = blockIdx.x;
    const int tid = threadIdx.x;
    if (bid < ROWS) {
        // ---- RMSNorm row ----
        const float* xr = x + (size_t)bid * D_MODEL;
        const float4 v0 = *reinterpret_cast<const float4*>(&xr[tid * 8]);
        const float4 v1 = *reinterpret_cast<const float4*>(&xr[tid * 8 + 4]);
        float ss = v0.x*v0.x + v0.y*v0.y + v0.z*v0.z + v0.w*v0.w
                 + v1.x*v1.x + v1.y*v1.y + v1.z*v1.z + v1.w*v1.w;
#pragma unroll
        for (int off = 32; off; off >>= 1) ss += __shfl_xor(ss, off);
        if ((tid & 63) == 0) red[tid >> 6] = ss;
        __syncthreads();
        const float rms = rsqrtf((red[0] + red[1] + red[2] + red[3]) * (1.0f / D_MODEL) + 1e-6f);
        const int cb = tid * 8;
        const size_t base = (size_t)bid * D_MODEL + cb;
        const float vals[8] = {v0.x, v0.y, v0.z, v0.w, v1.x, v1.y, v1.z, v1.w};
#pragma unroll
        for (int k = 0; k < 8; k += 2) {
            const uint16_t h0 = f2h(vals[k] * rms * wln[cb + k]);
            const uint16_t h1 = f2h(vals[k + 1] * rms * wln[cb + k + 1]);
            *reinterpret_cast<uint32_t*>(&outh[base + k]) = (uint32_t)h0 | ((uint32_t)h1 << 16);
        }
    } else {
        // ---- dequant Wq/Wk/Wv/Wo (all I=2048, mode 0) ----
        const int b2 = bid - ROWS;   // [0, 10240)
        const int* q; const float* s; uint16_t* out; int seg0;
        if (b2 < 4096)      { q = wq_q; s = wq_s; out = Wqkv;               seg0 = 0; }
        else if (b2 < 5120) { q = wk_q; s = wk_s; out = Wqkv + 2048 * 2048; seg0 = 4096; }
        else if (b2 < 6144) { q = wv_q; s = wv_s; out = Wqkv + 2560 * 2048; seg0 = 5120; }
        else                { q = wo_q; s = wo_s; out = Wo;                 seg0 = 6144; }
        dq_body(q, s, out, 2048, 0, (b2 - seg0) * 256 + tid);
    }
}
static constexpr int NORM_DQA_BLOCKS = ROWS + 10240;   // 12288

// ---------------------------------------------------------------------------
// RMSNorm standalone (post-attn norm).
// ---------------------------------------------------------------------------
__global__ __launch_bounds__(256)
void rmsnorm_kernel(const float* __restrict__ x, const float* __restrict__ wln,
                    uint16_t* __restrict__ out)
{
    __shared__ float red[4];
    const int row = blockIdx.x;
    const int tid = threadIdx.x;
    const float* xr = x + (size_t)row * D_MODEL;
    const float4 v0 = *reinterpret_cast<const float4*>(&xr[tid * 8]);
    const float4 v1 = *reinterpret_cast<const float4*>(&xr[tid * 8 + 4]);
    float ss = v0.x*v0.x + v0.y*v0.y + v0.z*v0.z + v0.w*v0.w
             + v1.x*v1.x + v1.y*v1.y + v1.z*v1.z + v1.w*v1.w;
#pragma unroll
    for (int off = 32; off; off >>= 1) ss += __shfl_xor(ss, off);
    if ((tid & 63) == 0) red[tid >> 6] = ss;
    __syncthreads();
    const float rms = rsqrtf((red[0] + red[1] + red[2] + red[3]) * (1.0f / D_MODEL) + 1e-6f);
    const int cb = tid * 8;
    const size_t base = (size_t)row * D_MODEL + cb;
    const float vals[8] = {v0.x, v0.y, v0.z, v0.w, v1.x, v1.y, v1.z, v1.w};
#pragma unroll
    for (int k = 0; k < 8; k += 2) {
        const uint16_t h0 = f2h(vals[k] * rms * wln[cb + k]);
        const uint16_t h1 = f2h(vals[k + 1] * rms * wln[cb + k + 1]);
        *reinterpret_cast<uint32_t*>(&out[base + k]) = (uint32_t)h0 | ((uint32_t)h1 << 16);
    }
}

// ---------------------------------------------------------------------------
// fp16 GEMM, 128x128 tile (fused SwiGLU epilogue, gate/up interleaved W).
// Round-6 verified: 875 TF = at the 128^2/2-barrier structure ceiling.
// Row-major block map (no xcd remap). BK=64, A+B dbuf, ONE barrier per K-tile.
// Both-sides swizzle: granule p at row r holds logical p^(r&7).
// ---------------------------------------------------------------------------
__global__ __launch_bounds__(256)
void gemm_f16_glu_kernel(const uint16_t* __restrict__ A, const uint16_t* __restrict__ W,
                         uint16_t* __restrict__ outh, int M, int N, int K)
{
    __shared__ uint16_t sA[2][128 * 64];
    __shared__ uint16_t sB[2][128 * 64];

    const int tid  = threadIdx.x;
    const int lane = tid & 63;
    const int wv   = tid >> 6;
    const int wm   = wv >> 1;
    const int wn   = wv & 1;
    const int quad = lane >> 4;
    const int l16  = lane & 15;

    const int nBn = N >> 7;
    const int bm  = blockIdx.x / nBn;
    const int bn  = blockIdx.x - bm * nBn;
    const int m0  = bm << 7;
    const int n0  = bn << 7;

    f32x4 acc[4][4];
#pragma unroll
    for (int i = 0; i < 4; i++)
#pragma unroll
        for (int j = 0; j < 4; j++)
            acc[i][j] = (f32x4){0.f, 0.f, 0.f, 0.f};

    const uint16_t* Ab = A + (size_t)m0 * K;
    const uint16_t* Wb = W + (size_t)n0 * K;

    auto stage = [&](int kt, int bsel) {
#pragma unroll
        for (int p = 0; p < 4; p++) {
            const int cb = p * 256 + wv * 64;          // wave-uniform chunk base
            const int c  = cb + lane;
            const int row = c >> 3;
            const int g   = (c & 7) ^ (row & 7);       // pre-swizzled source
            const size_t goff = (size_t)row * K + kt + g * 8;
            async_load16(Ab + goff, &sA[bsel][cb * 8]);
            async_load16(Wb + goff, &sB[bsel][cb * 8]);
        }
    };

    stage(0, 0);
    __syncthreads();

    const int nKt = K >> 6;
    for (int t = 0; t < nKt; t++) {
        const int cur = t & 1;
        if (t + 1 < nKt) stage((t + 1) << 6, cur ^ 1);
        const uint16_t* sAc = sA[cur];
        const uint16_t* sBc = sB[cur];
#pragma unroll
        for (int kk = 0; kk < 2; kk++) {
            const int gsw = ((kk * 4 + quad) ^ (l16 & 7)) * 8;   // swizzled read granule
            f16x8 bfv[4];
#pragma unroll
            for (int j = 0; j < 4; j++)
                bfv[j] = *reinterpret_cast<const f16x8*>(
                    &sBc[(wn * 64 + j * 16 + l16) * 64 + gsw]);
#pragma unroll
            for (int i = 0; i < 4; i++) {
                const f16x8 af = *reinterpret_cast<const f16x8*>(
                    &sAc[(wm * 64 + i * 16 + l16) * 64 + gsw]);
#pragma unroll
                for (int j = 0; j < 4; j++)
                    acc[i][j] = __builtin_amdgcn_mfma_f32_16x16x32_f16(af, bfv[j], acc[i][j], 0, 0, 0);
            }
        }
        __syncthreads();   // drains vmcnt (t+1 loads) + syncs reads of buf[cur]
    }

    // SwiGLU: j even = gate, j odd = up of same 16-col group.
    const int NH = N >> 1;
#pragma unroll
    for (int i = 0; i < 4; i++) {
        const int rowb = m0 + wm * 64 + i * 16 + quad * 4;
#pragma unroll
        for (int r = 0; r < 4; r++) {
            const size_t rr = (size_t)(rowb + r);
#pragma unroll
            for (int pjt = 0; pjt < 2; pjt++) {
                const float g = acc[i][2 * pjt][r];
                const float u = acc[i][2 * pjt + 1][r];
                const float a = (g / (1.0f + __expf(-g))) * u;
                const int cc = (n0 >> 1) + wn * 32 + pjt * 16 + l16;
                outh[rr * NH + cc] = f2h(a);
            }
        }
    }
}

// ---------------------------------------------------------------------------
// fp16 GEMM, 64x128 tile (fp32 out, +QKV-bias select / +resid). Round-3
// verified: BK=64, A+B dbuf, one barrier per K-tile, 48 KB LDS -> 3 blocks/CU.
// ---------------------------------------------------------------------------
__global__ __launch_bounds__(256)
void gemm_f16_m64_kernel(const uint16_t* __restrict__ A, const uint16_t* __restrict__ W,
                         const float* __restrict__ bq, const float* __restrict__ bk,
                         const float* __restrict__ bv, const float* __restrict__ resid,
                         float* __restrict__ outf, int M, int N, int K)
{
    __shared__ uint16_t sA[2][64 * 64];
    __shared__ uint16_t sB[2][128 * 64];

    const int tid  = threadIdx.x;
    const int lane = tid & 63;
    const int wv   = tid >> 6;
    const int quad = lane >> 4;
    const int l16  = lane & 15;

    const int nBn = N >> 7;
    const int bm  = blockIdx.x / nBn;
    const int bn  = blockIdx.x - bm * nBn;
    const int m0  = bm << 6;
    const int n0  = bn << 7;

    f32x4 acc[4][2];
#pragma unroll
    for (int i = 0; i < 4; i++)
#pragma unroll
        for (int j = 0; j < 2; j++)
            acc[i][j] = (f32x4){0.f, 0.f, 0.f, 0.f};

    const uint16_t* Ab = A + (size_t)m0 * K;
    const uint16_t* Wb = W + (size_t)n0 * K;

    auto stage = [&](int kt, int bsel) {
#pragma unroll
        for (int p = 0; p < 2; p++) {   // A tile: 512 chunks
            const int cb = p * 256 + wv * 64;
            const int c  = cb + lane;
            const int row = c >> 3;
            const int g   = (c & 7) ^ (row & 7);
            async_load16(Ab + (size_t)row * K + kt + g * 8, &sA[bsel][cb * 8]);
        }
#pragma unroll
        for (int p = 0; p < 4; p++) {   // B tile: 1024 chunks
            const int cb = p * 256 + wv * 64;
            const int c  = cb + lane;
            const int row = c >> 3;
            const int g   = (c & 7) ^ (row & 7);
            async_load16(Wb + (size_t)row * K + kt + g * 8, &sB[bsel][cb * 8]);
        }
    };

    stage(0, 0);
    __syncthreads();

    const int nKt = K >> 6;
    for (int t = 0; t < nKt; t++) {
        const int cur = t & 1;
        if (t + 1 < nKt) stage((t + 1) << 6, cur ^ 1);
        const uint16_t* sAc = sA[cur];
        const uint16_t* sBc = sB[cur];
#pragma unroll
        for (int kk = 0; kk < 2; kk++) {
            const int gsw = ((kk * 4 + quad) ^ (l16 & 7)) * 8;
            f16x8 bfv[2];
#pragma unroll
            for (int j = 0; j < 2; j++)
                bfv[j] = *reinterpret_cast<const f16x8*>(
                    &sBc[(wv * 32 + j * 16 + l16) * 64 + gsw]);
#pragma unroll
            for (int i = 0; i < 4; i++) {
                const f16x8 af = *reinterpret_cast<const f16x8*>(
                    &sAc[(i * 16 + l16) * 64 + gsw]);
#pragma unroll
                for (int j = 0; j < 2; j++)
                    acc[i][j] = __builtin_amdgcn_mfma_f32_16x16x32_f16(af, bfv[j], acc[i][j], 0, 0, 0);
            }
        }
        __syncthreads();
    }

    // epilogue: C row = quad*4+reg, col = lane&15 (m89-verified, dtype-indep)
#pragma unroll
    for (int i = 0; i < 4; i++) {
        const int rowb = m0 + i * 16 + quad * 4;
#pragma unroll
        for (int r = 0; r < 4; r++) {
            const size_t rr = (size_t)(rowb + r);
#pragma unroll
            for (int j = 0; j < 2; j++) {
                const int cc = n0 + wv * 32 + j * 16 + l16;
                float v = acc[i][j][r];
                if (bq) {   // QKV bias concat (boundaries are layout consts)
                    float bb;
                    if (cc < 2048)      bb = bq[cc];
                    else if (cc < 2560) bb = bk[cc - 2048];
                    else                bb = bv[cc - 2560];
                    v += bb;
                }
                if (resid) v += resid[rr * N + cc];
                outf[rr * N + cc] = v;
            }
        }
    }
}

// ---------------------------------------------------------------------------
// Mixed launch 2: prep_v (blocks [0,128)) || rope Q+K (blocks [128,10368)).
// Both read qkv only; independent outputs. prep_v first (longer blocks).
// Fast trig: freq = exp2(-d*log2(1e6)/64); __sincosf (hw sin/cos).
// ---------------------------------------------------------------------------
static constexpr int ROPE_Q_THREADS = ROWS * 16 * 64;   // 2,097,152
static constexpr int ROPE_THREADS   = ROPE_Q_THREADS + ROWS * 4 * 64;
static constexpr int PREPV_BLOCKS   = BATCH * 4 * (SEQ / 64);          // 128
static constexpr int ROPE_PREP_BLOCKS = PREPV_BLOCKS + ROPE_THREADS / 256;
static constexpr float LOG2_1E6_OVER_64 = 0.31143075889910283f;   // log2(1e6)/64

__global__ __launch_bounds__(256)
void rope_prep_kernel(const float* __restrict__ qkv, const int* __restrict__ offp,
                      uint16_t* __restrict__ Qb, uint16_t* __restrict__ Kb,
                      uint16_t* __restrict__ Vt)
{
    __shared__ uint16_t sh[128 * 72];
    const int tid = threadIdx.x;
    if (blockIdx.x < PREPV_BLOCKS) {
        // ---- V transpose: qkv fp32 -> fp16 V^T [(b*4+kvh)*128+dim][1024] ----
        const int sc  = blockIdx.x & 15;     // 16 chunks of 64 keys
        const int bk  = blockIdx.x >> 4;     // b*4+kvh
        const int b   = bk >> 2, kvh = bk & 3;
#pragma unroll
        for (int p = 0; p < 8; p++) {
            const int q4 = p * 256 + tid;    // 2048 float4s: 64 rows x 32
            const int sloc = q4 >> 5, d4 = (q4 & 31) * 4;
            const float4 v = *reinterpret_cast<const float4*>(
                &qkv[(size_t)(b * SEQ + sc * 64 + sloc) * N_QKV + 2560 + kvh * HD + d4]);
            sh[(d4 + 0) * 72 + sloc] = f2h(v.x);
            sh[(d4 + 1) * 72 + sloc] = f2h(v.y);
            sh[(d4 + 2) * 72 + sloc] = f2h(v.z);
            sh[(d4 + 3) * 72 + sloc] = f2h(v.w);
        }
        __syncthreads();
        const int d = tid >> 1, half = tid & 1;
        const size_t ob = ((size_t)(bk * 128 + d)) * SEQ + sc * 64 + half * 32;
        const uint16_t* srh = &sh[d * 72 + half * 32];
#pragma unroll
        for (int k = 0; k < 4; k++)
            *reinterpret_cast<uint4*>(&Vt[ob + k * 8]) =
                *reinterpret_cast<const uint4*>(&srh[k * 8]);
        return;
    }
    const int gidx = (blockIdx.x - PREPV_BLOCKS) * 256 + tid;
    if (gidx < ROPE_Q_THREADS) {
        const int idx = gidx;
        const int d   = idx & 63;
        const int h   = (idx >> 6) & 15;
        const int row = idx >> 10;
        const int b   = row >> 10;
        const int s   = row & (SEQ - 1);
        const float pos  = (float)(s + *offp);
        const float freq = exp2f(-(float)d * LOG2_1E6_OVER_64);
        float sn, cs;
        __sincosf(pos * freq, &sn, &cs);
        const size_t gb = (size_t)row * N_QKV + h * HD + d;
        const float x1 = qkv[gb];
        const float x2 = qkv[gb + 64];
        const float qscale = 0.08838834764831845f;   // 1/sqrt(128)
        const size_t ob = ((size_t)(b * 16 + h) * SEQ + s) * HD + d;
        Qb[ob]      = f2h((x1 * cs - x2 * sn) * qscale);
        Qb[ob + 64] = f2h((x2 * cs + x1 * sn) * qscale);
    } else {
        const int idx = gidx - ROPE_Q_THREADS;
        const int d   = idx & 63;
        const int kvh = (idx >> 6) & 3;
        const int row = idx >> 8;
        const int b   = row >> 10;
        const int s   = row & (SEQ - 1);
        const float pos  = (float)(s + *offp);
        const float freq = exp2f(-(float)d * LOG2_1E6_OVER_64);
        float sn, cs;
        __sincosf(pos * freq, &sn, &cs);
        const size_t gb = (size_t)row * N_QKV + 2048 + kvh * HD + d;
        const float x1 = qkv[gb];
        const float x2 = qkv[gb + 64];
        const size_t ob = ((size_t)(b * 4 + kvh) * SEQ + s) * HD + d;
        Kb[ob]      = f2h(x1 * cs - x2 * sn);
        Kb[ob + 64] = f2h(x2 * cs + x1 * sn);
    }
}

// ---------------------------------------------------------------------------
// Mixed launch 3: MFMA flash attention (blocks [0,512)) || dequant of
// gate/up/down (blocks [512, 512+33792)). Attention is compute/LDS-bound with
// an L2-resident KV set (4 MB); the gate/up/down dequant is ~150 MB of pure
// HBM streaming needed only before the GLU GEMM -> co-scheduled here the BW
// work hides under attention's runtime. Attn blocks dispatch first.
// Attn body = round-3 verified (dbuf K/V, one barrier/tile, wave-private sP).
// ---------------------------------------------------------------------------
static constexpr int ATTN_BLOCKS   = BATCH * HEADS * (SEQ / 64);   // 512
static constexpr int DQB_BLOCKS    = 3 * 11264;                    // 33792
static constexpr int ATTN_DQ_BLOCKS = ATTN_BLOCKS + DQB_BLOCKS;

__global__ __launch_bounds__(256)
void attn_dqB_kernel(const uint16_t* __restrict__ Qb, const uint16_t* __restrict__ Kb,
                     const uint16_t* __restrict__ Vt, uint16_t* __restrict__ att,
                     const int* __restrict__ gate_q, const float* __restrict__ gate_s,
                     const int* __restrict__ up_q, const float* __restrict__ up_s,
                     const int* __restrict__ down_q, const float* __restrict__ down_s,
                     uint16_t* __restrict__ Wgu, uint16_t* __restrict__ Wdown)
{
    __shared__ uint16_t sK[2][32 * 128];
    __shared__ uint16_t sV[2][128 * 32];
    __shared__ uint16_t sP[4 * 16 * 32];

    const int tid  = threadIdx.x;

    if (blockIdx.x >= ATTN_BLOCKS) {
        // ---- dequant gate/up/down ----
        const int b2 = blockIdx.x - ATTN_BLOCKS;   // [0, 33792)
        if (b2 < 11264)       dq_body(gate_q, gate_s, Wgu,   2048, 1, b2 * 256 + tid);
        else if (b2 < 22528)  dq_body(up_q,   up_s,   Wgu,   2048, 2, (b2 - 11264) * 256 + tid);
        else                  dq_body(down_q, down_s, Wdown, 5632, 0, (b2 - 22528) * 256 + tid);
        return;
    }

    const int lane = tid & 63;
    const int wv   = tid >> 6;
    const int quad = lane >> 4;
    const int l16  = lane & 15;
    const int qsw  = (quad ^ ((l16 >> 1) & 3)) * 8;   // swizzled V read granule

    const int bi  = blockIdx.x;
    const int sc  = 15 - (bi >> 5);      // big Q-tiles dispatched first
    const int bh  = bi & 31;
    const int b   = bh >> 4;
    const int h   = bh & 15;
    const int kvh = h >> 2;
    const int s0  = sc << 6;

    // Q fragments (A-layout) straight from global, once.
    f16x8 qf[4];
    {
        const size_t qb = ((size_t)(b * 16 + h) * SEQ + s0 + wv * 16 + l16) * HD;
#pragma unroll
        for (int ks = 0; ks < 4; ks++)
            qf[ks] = *reinterpret_cast<const f16x8*>(&Qb[qb + ks * 32 + quad * 8]);
    }

    float m_i[4], l_i[4];
#pragma unroll
    for (int r = 0; r < 4; r++) { m_i[r] = -1e30f; l_i[r] = 0.f; }
    f32x4 oacc[8];
#pragma unroll
    for (int dt = 0; dt < 8; dt++) oacc[dt] = (f32x4){0.f, 0.f, 0.f, 0.f};

    const size_t kb = (size_t)(b * 4 + kvh) * SEQ * HD;        // K base (elems)
    const size_t vb = (size_t)(b * 4 + kvh) * HD * SEQ;        // V^T base

    auto stageKV = [&](int t0, int bsel) {
#pragma unroll
        for (int p = 0; p < 2; p++) {
            const int cb = p * 256 + wv * 64;
            const int c  = cb + lane;
            const int krow = c >> 4;
            const int kcc  = (c & 15) ^ (krow & 7);
            async_load16(Kb + kb + (size_t)(t0 + krow) * HD + kcc * 8, &sK[bsel][cb * 8]);
            const int vrow = c >> 2;
            const int vcc  = (c & 3) ^ ((vrow >> 1) & 3);
            async_load16(Vt + vb + (size_t)vrow * SEQ + t0 + vcc * 8, &sV[bsel][cb * 8]);
        }
    };

    const int ntiles = 2 * sc + 2;
    stageKV(0, 0);
    __syncthreads();

    for (int tt = 0; tt < ntiles; tt++) {
        const int t0 = tt << 5;
        const int cur = tt & 1;
        if (tt + 1 < ntiles) stageKV((tt + 1) << 5, cur ^ 1);

        // S = Q·K^T
        f32x4 sacc[2];
        sacc[0] = (f32x4){0.f, 0.f, 0.f, 0.f};
        sacc[1] = (f32x4){0.f, 0.f, 0.f, 0.f};
#pragma unroll
        for (int ks = 0; ks < 4; ks++) {
#pragma unroll
            for (int jt = 0; jt < 2; jt++) {
                const int idx = (jt * 16 + l16) * 128 + (((ks * 4 + quad) ^ (l16 & 7)) * 8);
                const f16x8 kf = *reinterpret_cast<const f16x8*>(&sK[cur][idx]);
                sacc[jt] = __builtin_amdgcn_mfma_f32_16x16x32_f16(qf[ks], kf, sacc[jt], 0, 0, 0);
            }
        }

        // causal mask (only diagonal-region tiles)
        if (t0 >= s0) {
            const int rowg = s0 + wv * 16 + quad * 4;
#pragma unroll
            for (int jt = 0; jt < 2; jt++) {
                const int key = t0 + jt * 16 + l16;
#pragma unroll
                for (int r = 0; r < 4; r++)
                    if (key > rowg + r) sacc[jt][r] = -1e30f;
            }
        }

        // online softmax per reg (rows quad*4+reg; reduce over 16 l16 lanes)
        float alpha[4];
#pragma unroll
        for (int r = 0; r < 4; r++) {
            float mt = fmaxf(sacc[0][r], sacc[1][r]);
#pragma unroll
            for (int off = 8; off; off >>= 1) mt = fmaxf(mt, __shfl_xor(mt, off));
            const float mn = fmaxf(m_i[r], mt);
            alpha[r] = __expf(m_i[r] - mn);
            const float p0 = __expf(sacc[0][r] - mn);
            const float p1 = __expf(sacc[1][r] - mn);
            float ps = p0 + p1;
#pragma unroll
            for (int off = 8; off; off >>= 1) ps += __shfl_xor(ps, off);
            l_i[r] = l_i[r] * alpha[r] + ps;
            m_i[r] = mn;
            // write P: wave-private block, row = quad*4+r, key = jt*16+l16
            const int prow = quad * 4 + r;
            sP[wv * 512 + prow * 32 + 0 * 16 + l16] = f2h(p0);
            sP[wv * 512 + prow * 32 + 1 * 16 + l16] = f2h(p1);
        }

        // rescale O by alpha, then PV (sP same-wave RAW: in-order DS per wave)
#pragma unroll
        for (int dt = 0; dt < 8; dt++) {
#pragma unroll
            for (int r = 0; r < 4; r++) oacc[dt][r] *= alpha[r];
        }
        const f16x8 pf = *reinterpret_cast<const f16x8*>(&sP[wv * 512 + l16 * 32 + quad * 8]);
#pragma unroll
        for (int dt = 0; dt < 8; dt++) {
            const f16x8 vf = *reinterpret_cast<const f16x8*>(&sV[cur][(dt * 16 + l16) * 32 + qsw]);
            oacc[dt] = __builtin_amdgcn_mfma_f32_16x16x32_f16(pf, vf, oacc[dt], 0, 0, 0);
        }

        __syncthreads();   // drains next-tile loads; all reads of buf[cur] done
    }

    // final normalize + store (C-layout rows)
    float inv[4];
#pragma unroll
    for (int r = 0; r < 4; r++) inv[r] = 1.0f / l_i[r];
#pragma unroll
    for (int r = 0; r < 4; r++) {
        const size_t rowg = (size_t)(b * SEQ + s0 + wv * 16 + quad * 4 + r);
#pragma unroll
        for (int dt = 0; dt < 8; dt++)
            att[rowg * D_MODEL + h * HD + dt * 16 + l16] = f2h(oacc[dt][r] * inv[r]);
    }
}

// ---------------------------------------------------------------------------
extern "C" void kernel_launch(void* const* d_in, const int* in_sizes, int n_in,
                              void* d_out, int out_size, void* d_ws, size_t ws_size,
                              hipStream_t stream)
{
    (void)in_sizes; (void)n_in; (void)out_size; (void)ws_size;
    const float* x      = (const float*)d_in[0];
    const int*   wq_q   = (const int*)d_in[1];
    const float* wq_s   = (const float*)d_in[2];
    const float* bq     = (const float*)d_in[3];
    const int*   wk_q   = (const int*)d_in[4];
    const float* wk_s   = (const float*)d_in[5];
    const float* bk     = (const float*)d_in[6];
    const int*   wv_q   = (const int*)d_in[7];
    const float* wv_s   = (const float*)d_in[8];
    const float* bv     = (const float*)d_in[9];
    const int*   wo_q   = (const int*)d_in[10];
    const float* wo_s   = (const float*)d_in[11];
    const int*   gate_q = (const int*)d_in[12];
    const float* gate_s = (const float*)d_in[13];
    const int*   up_q   = (const int*)d_in[14];
    const float* up_s   = (const float*)d_in[15];
    const int*   down_q = (const int*)d_in[16];
    const float* down_s = (const float*)d_in[17];
    const float* w_in   = (const float*)d_in[18];
    const float* w_post = (const float*)d_in[19];
    const int*   offp   = (const int*)d_in[20];

    char* p = (char*)d_ws;
    auto alloc = [&](size_t bytes) {
        char* r = p;
        p += (bytes + 255) & ~(size_t)255;
        return r;
    };
    // persistent
    uint16_t* Wgu   = (uint16_t*)alloc((size_t)2 * D_FF * D_MODEL * 2);  // 46.1 MB
    uint16_t* Wdown = (uint16_t*)alloc((size_t)D_MODEL * D_FF * 2);      // 23.1 MB
    uint16_t* hbuf  = (uint16_t*)alloc((size_t)ROWS * D_MODEL * 2);      // h / h2
    float*    x2    = (float*)alloc((size_t)ROWS * D_MODEL * 4);
    // transient zone: Wqkv | Wo | qkv fp32  (aliased later)
    char* zone = alloc((size_t)N_QKV * D_MODEL * 2 +
                       (size_t)D_MODEL * D_MODEL * 2 +
                       (size_t)ROWS * N_QKV * 4 + 8192);
    uint16_t* Wqkv = (uint16_t*)zone;
    uint16_t* Wo   = Wqkv + (size_t)N_QKV * D_MODEL;
    float*    qkv  = (float*)(Wo + (size_t)D_MODEL * D_MODEL);
    // prep buffers alias Wqkv (dead after QKV GEMM): Q 8.39 + K 2.10 + V 2.10
    // = 12.58 MB = exactly sizeof(Wqkv).
    uint16_t* Qb = Wqkv;
    uint16_t* Kb = Qb + (size_t)BATCH * 16 * SEQ * HD;
    uint16_t* Vt = Kb + (size_t)BATCH * 4 * SEQ * HD;
    // attention output aliases qkv (dead after preps)
    uint16_t* att = (uint16_t*)qkv;
    // act aliases zone start (Wqkv/Wo/att all dead after O-proj); 23.1 MB
    uint16_t* act = (uint16_t*)zone;

    // rmsnorm1 || dequant Wqkv+Wo (both gate the QKV GEMM; independent)
    norm_dqA_kernel<<<NORM_DQA_BLOCKS, 256, 0, stream>>>(
        x, w_in, hbuf, wq_q, wq_s, wk_q, wk_s, wv_q, wv_s, wo_q, wo_s, Wqkv, Wo);

    // QKV: 64x128 tiles -> 768 blocks (3/CU); bias fused
    gemm_f16_m64_kernel<<<(ROWS / 64) * (N_QKV / 128), 256, 0, stream>>>(
        hbuf, Wqkv, bq, bk, bv, nullptr, qkv, ROWS, N_QKV, D_MODEL);

    // prep_v || rope Q+K (both read qkv only)
    rope_prep_kernel<<<ROPE_PREP_BLOCKS, 256, 0, stream>>>(qkv, offp, Qb, Kb, Vt);

    // attn || dequant gate/up/down (dequant hides under attn's compute)
    attn_dqB_kernel<<<ATTN_DQ_BLOCKS, 256, 0, stream>>>(
        Qb, Kb, Vt, att, gate_q, gate_s, up_q, up_s, down_q, down_s, Wgu, Wdown);

    // O-proj: 512 blocks (3/CU), resid fused
    gemm_f16_m64_kernel<<<(ROWS / 64) * (D_MODEL / 128), 256, 0, stream>>>(
        att, Wo, nullptr, nullptr, nullptr, x, x2, ROWS, D_MODEL, D_MODEL);

    rmsnorm_kernel<<<ROWS, 256, 0, stream>>>(x2, w_post, hbuf);

    // GU: 128x128 tiles, 1408 blocks (at structure ceiling, 875 TF)
    gemm_f16_glu_kernel<<<(ROWS / 128) * (2 * D_FF / 128), 256, 0, stream>>>(
        hbuf, Wgu, act, ROWS, 2 * D_FF, D_MODEL);

    // down: 512 blocks (3/CU), resid (x2) fused, writes final output
    gemm_f16_m64_kernel<<<(ROWS / 64) * (D_MODEL / 128), 256, 0, stream>>>(
        act, Wdown, nullptr, nullptr, nullptr, x2, (float*)d_out, ROWS, D_MODEL, D_FF);
}